// Round 15
// baseline (56.216 us; speedup 1.0000x reference)
//
#include <hip/hip_runtime.h>
#include <hip/hip_bf16.h>

typedef __attribute__((ext_vector_type(4)))  float f32x4;
typedef __attribute__((ext_vector_type(16))) float f32x16;
typedef __attribute__((ext_vector_type(8)))  short bf16x8;
typedef __attribute__((ext_vector_type(4)))  unsigned u32x4;

#define S_LEN 4096
#define HEAD_D 64
#define WIN 256
#define QBLK 128
#define KVBLK 64
#define KSTR 72   // k row stride (shorts); b128 reads conflict-free (measured 0)
#define VSTR 72   // vt row stride (shorts), [d][key'] key' = key bits2<->3 swapped
#define QSCALE 0.18033688f   // log2(e)/8 folded into Q; no numerator shift

#define KBYTES (KVBLK * KSTR * 2)        // 9216 B per tile-buffer (K and V alike)
#define KELEM  (KVBLK * KSTR)            // 4608 shorts per K buffer
#define VELEM  (HEAD_D * VSTR)           // 4608 shorts per V buffer
#define LPAR_OFF (8 * KBYTES)            // 73728: after 4 K-bufs + 4 V-bufs
#define SMEM_TOTAL (LPAR_OFF + 2 * 4 * 32 * 4)   // +1 KB l partials = 74752

static __device__ __forceinline__ unsigned cvt2(float lo, float hi) {
  unsigned r;
  asm("v_cvt_pk_bf16_f32 %0, %1, %2" : "=v"(r) : "v"(lo), "v"(hi));
  return r;
}

// Publish barrier: drains LDS only; in-flight global prefetch loads ride across.
#define PUB_BARRIER() do {                              \
    __builtin_amdgcn_sched_barrier(0);                  \
    asm volatile("s_waitcnt lgkmcnt(0)" ::: "memory");  \
    __builtin_amdgcn_s_barrier();                       \
    __builtin_amdgcn_sched_barrier(0);                  \
  } while (0)

// Period-2 schedule: one barrier per TWO 64-key tiles (4-buffer ring, 74.8 KB dynamic
// LDS). Between barriers each wave runs two independent QK->SM->PV chains (s_a, s_b)
// -> 2x ILP and half the convoys vs R11. 8 waves = 4 qg x 2 kh, 32q x 32k per chain.
__global__ __launch_bounds__(512, 2)   // cap 256 >= demand ~120 (never cap below demand)
void swa_fwd(const float* __restrict__ Q, const float* __restrict__ K,
             const float* __restrict__ V, float* __restrict__ O) {
  extern __shared__ __align__(16) char smem[];

  const int tid  = threadIdx.x;
  const int widx = tid >> 6;
  const int lane = tid & 63;
  const int hi   = lane >> 5;
  const int c    = lane & 31;
  const int qg   = widx & 3;
  const int kh   = widx >> 2;
  const int kho  = kh * 32;

  // XCD swizzle: 4 contiguous bh per XCD, qb fastest.
  const int pb  = blockIdx.x;
  const int bh  = (pb & 7) * 4 + ((pb >> 3) >> 5);
  const int qb  = (pb >> 3) & 31;
  const int bq0 = qb * QBLK;
  const int q0w = bq0 + qg * 32;

  const size_t base = (size_t)bh * S_LEN * HEAD_D;
  const float* Qp = Q + base;
  const float* Kp = K + base;
  const float* Vp = V + base;
  float*       Op = O + base;

  const f32x16 Z16 = {0.f,0.f,0.f,0.f,0.f,0.f,0.f,0.f,0.f,0.f,0.f,0.f,0.f,0.f,0.f,0.f};

  // ---- Q B-fragments ----
  bf16x8 aq[4];
  {
    const float* qr = Qp + (size_t)(q0w + c) * HEAD_D + hi * 8;
    #pragma unroll
    for (int ch = 0; ch < 4; ++ch) {
      f32x4 x0 = *(const f32x4*)(qr + ch * 16);
      f32x4 x1 = *(const f32x4*)(qr + ch * 16 + 4);
      u32x4 au;
      au[0] = cvt2(x0[0] * QSCALE, x0[1] * QSCALE);
      au[1] = cvt2(x0[2] * QSCALE, x0[3] * QSCALE);
      au[2] = cvt2(x1[0] * QSCALE, x1[1] * QSCALE);
      au[3] = cvt2(x1[2] * QSCALE, x1[3] * QSCALE);
      aq[ch] = __builtin_bit_cast(bf16x8, au);
    }
  }

  f32x16 acc0 = Z16, acc1 = Z16;
  float lsA = 0.f, lsB = 0.f;

  const int lo   = max(0, bq0 - WIN);
  const int khiB = min(S_LEN, bq0 + QBLK + WIN);
  const int nt   = (khiB - lo) >> 6;   // {6,8,10}: always even
  const int np   = nt >> 1;            // periods: {3,4,5}

  // staging lane assignment (512 threads; one K f32x4-pair + one V key-pair per thread)
  const int krow  = tid >> 3;
  const int kc8   = (tid & 7) << 3;
  const int key2  = (tid & 31) << 1;
  const int key2p = (key2 & ~12) | ((key2 & 4) << 1) | ((key2 & 8) >> 1);  // bits 2<->3
  const int vd4   = (tid >> 5) << 2;

  // hoisted LDS bases (buffer index becomes imm/const offset)
  short* const ksh = (short*)smem;
  short* const vsh = (short*)(smem + 4 * KBYTES);
  const short* const krd = ksh + (kho + c) * KSTR + hi * 8;
  const short* const vrd = vsh + c * VSTR + kho + hi * 8;
  short* const kwr = ksh + krow * KSTR + kc8;
  short* const vwr = vsh + vd4 * VSTR + key2p;

  unsigned koff = (unsigned)(lo + krow) * HEAD_D + kc8;
  unsigned voff = (unsigned)(lo + key2) * HEAD_D + vd4;

  f32x4 ka0, ka1, va0, va1;   // staging regs (16), reused A-then-B within a period
  #define LOAD_TILE() do {                          \
    ka0 = *(const f32x4*)(Kp + koff);               \
    ka1 = *(const f32x4*)(Kp + koff + 4);           \
    va0 = *(const f32x4*)(Vp + voff);               \
    va1 = *(const f32x4*)(Vp + voff + HEAD_D);      \
    koff += KVBLK * HEAD_D;                         \
    voff += KVBLK * HEAD_D;                         \
  } while (0)

  #define STAGE_TO(BUF) do {                                        \
    u32x4 kw;                                                       \
    kw[0] = cvt2(ka0[0], ka0[1]);                                   \
    kw[1] = cvt2(ka0[2], ka0[3]);                                   \
    kw[2] = cvt2(ka1[0], ka1[1]);                                   \
    kw[3] = cvt2(ka1[2], ka1[3]);                                   \
    *(u32x4*)&kwr[(BUF) * KELEM] = kw;                              \
    _Pragma("unroll")                                               \
    for (int j = 0; j < 4; ++j)                                     \
      *(unsigned*)&vwr[(BUF) * VELEM + j * VSTR] = cvt2(va0[j], va1[j]); \
  } while (0)

  #define SOFTMAX(SV, REL) do {                                               \
    if ((REL) >= -224 && (REL) <= 224) {                                      \
      _Pragma("unroll")                                                       \
      for (int g = 0; g < 16; g += 2) {                                       \
        const float p0 = __builtin_amdgcn_exp2f((SV)[g]);                     \
        const float p1 = __builtin_amdgcn_exp2f((SV)[g + 1]);                 \
        (SV)[g] = p0; (SV)[g + 1] = p1; lsA += p0; lsB += p1;                 \
      }                                                                       \
    } else {                                                                  \
      const int bm_ = (REL) + 4 * hi - c + WIN;                               \
      _Pragma("unroll")                                                       \
      for (int g = 0; g < 16; ++g) {                                          \
        const int ro_ = (g & 3) + 8 * (g >> 2);                               \
        const float p = ((unsigned)(bm_ + ro_) <= 2u * WIN)                   \
                          ? __builtin_amdgcn_exp2f((SV)[g]) : 0.f;            \
        (SV)[g] = p; if (g & 1) lsB += p; else lsA += p;                      \
      }                                                                       \
    }                                                                         \
  } while (0)

  #define PV(SV, BUF) do {                                                    \
    __builtin_amdgcn_s_setprio(1);                                            \
    _Pragma("unroll")                                                         \
    for (int kt = 0; kt < 2; ++kt) {                                          \
      u32x4 pau;                                                              \
      _Pragma("unroll")                                                       \
      for (int p2 = 0; p2 < 4; ++p2)                                          \
        pau[p2] = cvt2((SV)[kt * 8 + 2 * p2], (SV)[kt * 8 + 2 * p2 + 1]);     \
      const bf16x8 pa = __builtin_bit_cast(bf16x8, pau);                      \
      bf16x8 bv0 = *(const bf16x8*)&vrd[(BUF) * VELEM + kt * 16];             \
      acc0 = __builtin_amdgcn_mfma_f32_32x32x16_bf16(pa, bv0, acc0, 0, 0, 0); \
      bf16x8 bv1 = *(const bf16x8*)&vrd[(BUF) * VELEM + kt * 16 + 32 * VSTR]; \
      acc1 = __builtin_amdgcn_mfma_f32_32x32x16_bf16(pa, bv1, acc1, 0, 0, 0); \
    }                                                                         \
    __builtin_amdgcn_s_setprio(0);                                            \
  } while (0)

  // PERIOD PP (tiles 2PP, 2PP+1) on buffer pair PAIR; stages next pair.
  #define PERIOD(PP, PAIR) do {                                               \
    const int BA = 2 * (PAIR), BB = BA + 1;                                   \
    const int TGA = 2 * ((PAIR) ^ 1), TGB = TGA + 1;                          \
    const bool more_ = (PP) + 1 < np;                                         \
    const int rel_a = lo + ((PP) << 7) + kho - q0w;                           \
    if (more_) LOAD_TILE();              /* tile 2PP+2: latency under QK */   \
    f32x16 s_a = Z16, s_b = Z16;                                              \
    __builtin_amdgcn_s_setprio(1);       /* two independent QK chains */      \
    _Pragma("unroll")                                                         \
    for (int ch = 0; ch < 4; ++ch) {                                          \
      bf16x8 akfA = *(const bf16x8*)&krd[BA * KELEM + ch * 16];               \
      s_a = __builtin_amdgcn_mfma_f32_32x32x16_bf16(akfA, aq[ch], s_a, 0,0,0);\
      bf16x8 akfB = *(const bf16x8*)&krd[BB * KELEM + ch * 16];               \
      s_b = __builtin_amdgcn_mfma_f32_32x32x16_bf16(akfB, aq[ch], s_b, 0,0,0);\
    }                                                                         \
    __builtin_amdgcn_s_setprio(0);                                            \
    if (more_) {                                                              \
      STAGE_TO(TGA);                     /* vmcnt wait covered by QK */       \
      LOAD_TILE();                       /* tile 2PP+3: covered by SM+PV(a) */\
    }                                                                         \
    SOFTMAX(s_a, rel_a);                                                      \
    PV(s_a, BA);                                                              \
    if (more_) STAGE_TO(TGB);                                                 \
    SOFTMAX(s_b, rel_a + 64);                                                 \
    PV(s_b, BB);                                                              \
    if (more_) PUB_BARRIER();                                                 \
  } while (0)

  // prologue: stage tiles 0,1 into bufs 0,1 (two exposed vmcnt waits, once)
  LOAD_TILE();
  STAGE_TO(0);
  LOAD_TILE();
  STAGE_TO(1);
  PUB_BARRIER();

  for (int pp = 0; pp < np; pp += 2) {   // pair bit = pp%2, compile-time per body
    PERIOD(pp, 0);
    if (pp + 1 < np) PERIOD(pp + 1, 1);
  }

  // ---- epilogue: merge kh halves; overlay on dead K/V LDS ----
  float lsum = lsA + lsB;
  lsum += __shfl_xor(lsum, 32);
  __syncthreads();                               // all tile reads done -> overlay safe
  float* o_mrg = (float*)smem;                   // [4][32][64] f32 = 32 KB
  float* l_par = (float*)(smem + LPAR_OFF);      // [2 kh][4 qg][32]
  if (hi == 0) l_par[(kh * 4 + qg) * 32 + c] = lsum;
  if (kh == 0) {
    #pragma unroll
    for (int g = 0; g < 16; ++g) {
      const int qrow = (g & 3) + 8 * (g >> 2) + 4 * hi;
      o_mrg[(qg * 32 + qrow) * HEAD_D + c]      = acc0[g];
      o_mrg[(qg * 32 + qrow) * HEAD_D + 32 + c] = acc1[g];
    }
  }
  __syncthreads();
  if (kh == 1) {
    if (hi == 0) l_par[qg * 32 + c] = 1.0f / (l_par[qg * 32 + c] + l_par[(4 + qg) * 32 + c]);
    __asm__ volatile("s_waitcnt lgkmcnt(0)" ::: "memory");
    __builtin_amdgcn_sched_barrier(0);
    #pragma unroll
    for (int g = 0; g < 16; ++g) {
      const int qrow = (g & 3) + 8 * (g >> 2) + 4 * hi;
      const float iv = l_par[qg * 32 + qrow];
      float* orow = Op + (size_t)(q0w + qrow) * HEAD_D;
      orow[c]      = (o_mrg[(qg * 32 + qrow) * HEAD_D + c]      + acc0[g]) * iv;
      orow[32 + c] = (o_mrg[(qg * 32 + qrow) * HEAD_D + 32 + c] + acc1[g]) * iv;
    }
  }
}

extern "C" void kernel_launch(void* const* d_in, const int* in_sizes, int n_in,
                              void* d_out, int out_size, void* d_ws, size_t ws_size,
                              hipStream_t stream) {
  const float* q = (const float*)d_in[0];
  const float* k = (const float*)d_in[1];
  const float* v = (const float*)d_in[2];
  float* o = (float*)d_out;
  // opt in to >64KB dynamic LDS (host-side attribute, graph-capture safe)
  static int attr_done = 0;
  hipFuncSetAttribute((const void*)swa_fwd,
                      hipFuncAttributeMaxDynamicSharedMemorySize, SMEM_TOTAL);
  (void)attr_done;
  const int blocks = 2 * 16 * (S_LEN / QBLK);  // 1024
  swa_fwd<<<dim3(blocks), dim3(512), SMEM_TOTAL, stream>>>(q, k, v, o);
}